// Round 1
// baseline (435.658 us; speedup 1.0000x reference)
//
#include <hip/hip_runtime.h>
#include <stdint.h>

#define B_DIM 4
#define Z_DIM 128
#define L_DIM 64
#define P_DIM 65536   // 256*256
#define CHUNK 128     // pixels staged per chunk

typedef short sh8  __attribute__((ext_vector_type(8)));   // 8 bf16 = 16B (MFMA A/B frag)
typedef short sh4v __attribute__((ext_vector_type(4)));   // 4 bf16 = 8B
typedef float f32x4 __attribute__((ext_vector_type(4)));  // MFMA C/D frag

// fp32 -> bf16 RNE
__device__ __forceinline__ unsigned short bfc(float x) {
  uint32_t u = __float_as_uint(x);
  u += 0x7FFFu + ((u >> 16) & 1u);
  return (unsigned short)(u >> 16);
}

// XOR swizzle (guide G4): row stride = 128 ushorts (256B). XOR bits 3..5 of the
// ushort index with (row&7) -> spreads the 16B frag slots of 8 rows across banks.
__device__ __forceinline__ int swz(int row, int k) {
  return (row * CHUNK + k) ^ ((row & 7) << 3);
}

// ---------------------------------------------------------------------------
// Pass 1: fused stream over pred/pred_mv.
//   grid = (NB, 4 batches, 2 views), block = 256.
// Per chunk of 128 pixels: stage masked bf16 tile [128z][128px] + onehot tile
// [64l][128px] in LDS, then MFMA:
//   Gram  G[zi][zj]   += tile_row(zi) . tile_row(zj)      (wave w owns zi in {2w,2w+1})
//   Sum   S[l][z]     += oh_row(l)    . tile_row(z)       (wave w owns label-tile w)
// Per-pixel |a|^2 accumulated in fp32 -> per-label sq sums (exact path for sim).
// Partials (36 upper-tri Gram tiles + 32 S tiles + 64 sq) stored to d_ws.
// ---------------------------------------------------------------------------
__global__ __launch_bounds__(256, 2)
void pass1_k(const float* __restrict__ pred, const float* __restrict__ predmv,
             const int* __restrict__ gt, const uint8_t* __restrict__ fov,
             float* __restrict__ gpart, float* __restrict__ spart,
             float* __restrict__ qpart, int NB, int nchunks) {
  const int cb = blockIdx.x, b = blockIdx.y, view = blockIdx.z;
  const float* __restrict__ src = (view ? predmv : pred) + (size_t)b * Z_DIM * P_DIM;
  const int* __restrict__ gtb = gt + (size_t)b * P_DIM;
  const uint8_t* __restrict__ fovb = fov + (size_t)b * P_DIM;
  const int t = threadIdx.x;
  const int wid = t >> 6, lane = t & 63;

  __shared__ __align__(16) unsigned short tile[Z_DIM * CHUNK]; // 32 KB
  __shared__ __align__(16) unsigned short oh[L_DIM * CHUNK];   // 16 KB
  __shared__ float sqpx[CHUNK];
  __shared__ float sqseg[L_DIM];
  __shared__ int   lab[CHUNK];
  __shared__ float warr[CHUNK];

  if (t < L_DIM) sqseg[t] = 0.f;

  f32x4 accg[2][8];  // Gram: rows ti=2*wid+i, cols tj=0..7 (static indexing only)
  f32x4 accs[8];     // S: label-tile wid x z-tiles
  const f32x4 zero4 = {0.f, 0.f, 0.f, 0.f};
#pragma unroll
  for (int i = 0; i < 2; ++i)
#pragma unroll
    for (int j = 0; j < 8; ++j) accg[i][j] = zero4;
#pragma unroll
  for (int j = 0; j < 8; ++j) accs[j] = zero4;

  const int pb0 = cb * (P_DIM / NB);
  const int zr  = t >> 5;          // 0..7 (z row group)
  const int px4 = (t & 31) << 2;   // pixel*4 within chunk

  for (int c = 0; c < nchunks; ++c) {
    const int pb = pb0 + c * CHUNK;
    __syncthreads();  // previous chunk's MFMA reads done
    {  // zero onehot tile
      uint32_t* ohw = (uint32_t*)oh;
#pragma unroll
      for (int i = 0; i < (L_DIM * CHUNK / 2) / 256; ++i) ohw[t + i * 256] = 0u;
    }
    if (t < CHUNK) {
      const int g = gtb[pb + t];
      const int w = (fovb[pb + t] != 0 && g != 0) ? 1 : 0;
      lab[t]  = g & 63;
      warr[t] = (float)w;
      sqpx[t] = 0.f;
    }
    __syncthreads();
    if (t < CHUNK && warr[t] != 0.f)
      oh[swz(lab[t], t)] = 0x3F80;  // bf16 1.0

    // ---- stage: coalesced fp32 plane reads -> masked bf16 LDS tile ----
    float s0 = 0.f, s1 = 0.f, s2 = 0.f, s3 = 0.f;
    const float w0 = warr[px4], w1 = warr[px4 + 1], w2 = warr[px4 + 2], w3 = warr[px4 + 3];
#pragma unroll
    for (int r = 0; r < 16; ++r) {
      const int z = zr + r * 8;
      const float4 v = *(const float4*)(src + (size_t)z * P_DIM + pb + px4);
      const float a0 = v.x * w0, a1 = v.y * w1, a2 = v.z * w2, a3 = v.w * w3;
      s0 += a0 * a0; s1 += a1 * a1; s2 += a2 * a2; s3 += a3 * a3;
      sh4v pk;
      pk.x = (short)bfc(a0); pk.y = (short)bfc(a1);
      pk.z = (short)bfc(a2); pk.w = (short)bfc(a3);
      *(sh4v*)&tile[swz(z, px4)] = pk;
    }
    atomicAdd(&sqpx[px4 + 0], s0); atomicAdd(&sqpx[px4 + 1], s1);
    atomicAdd(&sqpx[px4 + 2], s2); atomicAdd(&sqpx[px4 + 3], s3);
    __syncthreads();
    if (t < CHUNK) atomicAdd(&sqseg[lab[t]], sqpx[t]);  // sqpx already masked

    // ---- MFMA over K=128 (4 ksteps of 32) ----
#pragma unroll
    for (int ks = 0; ks < 4; ++ks) {
      const int kb = ks * 32 + ((lane >> 4) << 3);
      sh8 fz[8], fa[2], ohf;
#pragma unroll
      for (int zt = 0; zt < 8; ++zt)
        fz[zt] = *(const sh8*)&tile[swz(zt * 16 + (lane & 15), kb)];
#pragma unroll
      for (int i = 0; i < 2; ++i)
        fa[i] = *(const sh8*)&tile[swz((2 * wid + i) * 16 + (lane & 15), kb)];
      ohf = *(const sh8*)&oh[swz(wid * 16 + (lane & 15), kb)];
#pragma unroll
      for (int i = 0; i < 2; ++i)
#pragma unroll
        for (int tj = 0; tj < 8; ++tj)
          accg[i][tj] = __builtin_amdgcn_mfma_f32_16x16x32_bf16(fa[i], fz[tj], accg[i][tj], 0, 0, 0);
#pragma unroll
      for (int zt = 0; zt < 8; ++zt)
        accs[zt] = __builtin_amdgcn_mfma_f32_16x16x32_bf16(ohf, fz[zt], accs[zt], 0, 0, 0);
    }
  }
  __syncthreads();

  // ---- flush partials (upper-triangular Gram tiles only) ----
  const size_t slot = (size_t)(view * 4 + b) * NB + cb;
  float* gp = gpart + slot * (36 * 256);
#pragma unroll
  for (int i = 0; i < 2; ++i) {
    const int ti = 2 * wid + i;
#pragma unroll
    for (int tj = 0; tj < 8; ++tj) {
      if (tj >= ti) {  // wave-uniform branch
        const int lin = ti * 8 - (ti * (ti - 1)) / 2 + (tj - ti);
        float* dst = gp + lin * 256 + (lane >> 4) * 64 + (lane & 15);
#pragma unroll
        for (int r = 0; r < 4; ++r) dst[r * 16] = accg[i][tj][r];
      }
    }
  }
  float* sp = spart + slot * (32 * 256) + wid * (8 * 256);
#pragma unroll
  for (int zt = 0; zt < 8; ++zt) {
    float* dst = sp + zt * 256 + (lane >> 4) * 64 + (lane & 15);
#pragma unroll
    for (int r = 0; r < 4; ++r) dst[r * 16] = accs[zt][r];
  }
  if (t < L_DIM) qpart[slot * 64 + t] = sqseg[t];
}

// ---------------------------------------------------------------------------
// n_l counting (per batch,label masked pixel counts)
// ---------------------------------------------------------------------------
__global__ void nl_k(const int* __restrict__ gt, const uint8_t* __restrict__ fov,
                     int* __restrict__ nl) {
  __shared__ int cnt[L_DIM];
  const int t = threadIdx.x;
  if (t < L_DIM) cnt[t] = 0;
  __syncthreads();
  const int b = blockIdx.x >> 4;
  const int base = b * P_DIM + (blockIdx.x & 15) * 4096;
  for (int i = 0; i < 16; ++i) {
    const int p = base + i * 256 + t;
    const int g = gt[p];
    if (fov[p] != 0 && g != 0) atomicAdd(&cnt[g & 63], 1);
  }
  __syncthreads();
  if (t < L_DIM) atomicAdd(&nl[b * L_DIM + t], cnt[t]);
}

// ---------------------------------------------------------------------------
// Reduce partial buffers
// gred[2][36][256], sred[2][4][4][8][256], qred[2][4][64]
// ---------------------------------------------------------------------------
__global__ void reduce_k(const float* __restrict__ gpart, const float* __restrict__ spart,
                         const float* __restrict__ qpart, float* __restrict__ gred,
                         float* __restrict__ sred, float* __restrict__ qred, int NB) {
  int id = blockIdx.x * blockDim.x + threadIdx.x;
  const int GE = 2 * 36 * 256, SE = 2 * 4 * 32 * 256, QE = 2 * 4 * 64;
  if (id < GE) {
    const int v = id / (36 * 256), e = id % (36 * 256);
    const float* p = gpart + (size_t)v * 4 * NB * (36 * 256) + e;
    float acc = 0.f;
    for (int s = 0; s < 4 * NB; ++s) acc += p[(size_t)s * (36 * 256)];
    gred[id] = acc;
  } else if ((id -= GE) < SE) {
    const int vb = id / (32 * 256);
    const float* p = spart + (size_t)vb * NB * (32 * 256) + (id % (32 * 256));
    float acc = 0.f;
    for (int s = 0; s < NB; ++s) acc += p[(size_t)s * (32 * 256)];
    sred[id] = acc;
  } else if ((id -= SE) < QE) {
    const int vb = id / 64;
    const float* p = qpart + (size_t)vb * NB * 64 + (id % 64);
    float acc = 0.f;
    for (int s = 0; s < NB; ++s) acc += p[(size_t)s * 64];
    qred[id] = acc;
  }
}

// ---------------------------------------------------------------------------
// Finalize: sim + std + cov -> single scalar. 1 block x 256 threads, fp64 accum.
// sred index: (((v*4+b)*4 + (l>>4))*8 + (z>>4))*256 + (l&15)*16 + (z&15)
// ---------------------------------------------------------------------------
__global__ void finalize_k(const float* __restrict__ gred, const float* __restrict__ sred,
                           const float* __restrict__ qred, const int* __restrict__ nl,
                           float* __restrict__ out) {
  const int t = threadIdx.x;
  __shared__ double red[256];
  __shared__ double mu[2][128];
  __shared__ double scal[8];
  __shared__ int tti[36], ttj[36];
  if (t == 0) {
    int idx = 0;
    for (int ti = 0; ti < 8; ++ti)
      for (int tj = ti; tj < 8; ++tj) { tti[idx] = ti; ttj[idx] = tj; ++idx; }
  }
  const double nlv = (double)nl[t];

  red[t] = nlv;  // n
  __syncthreads();
  for (int s = 128; s > 0; s >>= 1) { if (t < s) red[t] += red[t + s]; __syncthreads(); }
  if (t == 0) scal[0] = red[0];
  __syncthreads();
  const double n = scal[0];

  red[t] = nlv * nlv;  // count
  __syncthreads();
  for (int s = 128; s > 0; s >>= 1) { if (t < s) red[t] += red[t + s]; __syncthreads(); }
  if (t == 0) scal[1] = red[0];
  __syncthreads();

  {  // sim numerator
    const int b = t >> 6, l = t & 63;
    const double sqa = (double)qred[(0 * 4 + b) * 64 + l];
    const double sqm = (double)qred[(1 * 4 + b) * 64 + l];
    double dot = 0.0;
    for (int z = 0; z < 128; ++z) {
      const int e = ((l & 15) << 4) + (z & 15);
      const int ia = (((0 * 4 + b) * 4 + (l >> 4)) * 8 + (z >> 4)) * 256 + e;
      const int im = (((1 * 4 + b) * 4 + (l >> 4)) * 8 + (z >> 4)) * 256 + e;
      dot += (double)sred[ia] * (double)sred[im];
    }
    red[t] = nlv * (sqa + sqm) - 2.0 * dot;
  }
  __syncthreads();
  for (int s = 128; s > 0; s >>= 1) { if (t < s) red[t] += red[t + s]; __syncthreads(); }
  if (t == 0) scal[2] = red[0];
  __syncthreads();

  {  // mu
    const int v = t >> 7, z = t & 127;
    double s = 0.0;
    for (int b = 0; b < 4; ++b)
      for (int l = 0; l < 64; ++l)
        s += (double)sred[(((v * 4 + b) * 4 + (l >> 4)) * 8 + (z >> 4)) * 256 + ((l & 15) << 4) + (z & 15)];
    mu[v][z] = s / n;
  }
  __syncthreads();

  {  // std
    const int v = t >> 7, z = t & 127;
    const int zt = z >> 4;
    const int lin = zt * 8 - (zt * (zt - 1)) / 2;
    const double gd = (double)gred[v * 9216 + lin * 256 + (z & 15) * 17];
    const double var = (gd - n * mu[v][z] * mu[v][z]) / (n - 1.0);
    const double sd = sqrt(var + 1e-4);
    const double rr = 1.0 - sd;
    red[t] = rr > 0.0 ? rr : 0.0;
  }
  __syncthreads();
  for (int s = 64; s > 0; s >>= 1) { if ((t & 127) < s) red[t] += red[t + s]; __syncthreads(); }
  if (t == 0)   scal[3] = red[0] / 128.0;
  if (t == 128) scal[4] = red[128] / 128.0;
  __syncthreads();

  for (int v = 0; v < 2; ++v) {  // cov: 2*sum_{i<j} cov_ij^2 / Z
    double acc = 0.0;
    for (int idx = t; idx < 9216; idx += 256) {
      const int lin = idx >> 8, e = idx & 255;
      const int i = tti[lin] * 16 + (e >> 4), j = ttj[lin] * 16 + (e & 15);
      if (i < j) {
        const double g = (double)gred[v * 9216 + idx];
        const double cv = (g - n * mu[v][i] * mu[v][j]) / (n - 1.0);
        acc += 2.0 * cv * cv;
      }
    }
    red[t] = acc;
    __syncthreads();
    for (int s = 128; s > 0; s >>= 1) { if (t < s) red[t] += red[t + s]; __syncthreads(); }
    if (t == 0) scal[5 + v] = red[0] / 128.0;
    __syncthreads();
  }

  if (t == 0)
    out[0] = (float)(scal[2] / scal[1] + scal[3] + scal[4] + scal[5] + scal[6]);
}

// ---------------------------------------------------------------------------
extern "C" void kernel_launch(void* const* d_in, const int* in_sizes, int n_in,
                              void* d_out, int out_size, void* d_ws, size_t ws_size,
                              hipStream_t stream) {
  const float*  pred   = (const float*)d_in[0];
  const float*  predmv = (const float*)d_in[1];
  const int*    gt     = (const int*)d_in[2];
  const uint8_t* fov   = (const uint8_t*)d_in[3];   // jnp bool = 1 byte/elem
  float* out = (float*)d_out;

  // NB = blocks per (view,batch); shrink if workspace is small.
  int NB = 64;
  const size_t per_slot = 36 * 256 + 32 * 256 + 64;  // floats per block slot
  const size_t reserved = (size_t)(2 * 36 * 256 + 2 * 4 * 32 * 256 + 2 * 4 * 64 + 256) * 4 + 1024;
  while (NB > 1 && (size_t)8 * NB * per_slot * 4 + reserved > ws_size) NB >>= 1;

  float* ws    = (float*)d_ws;
  float* gpart = ws;
  float* spart = gpart + (size_t)8 * NB * (36 * 256);
  float* qpart = spart + (size_t)8 * NB * (32 * 256);
  float* gred  = qpart + (size_t)8 * NB * 64;
  float* sred  = gred + 2 * 36 * 256;
  float* qred  = sred + 2 * 4 * 32 * 256;
  int*   nl    = (int*)(qred + 2 * 4 * 64);

  hipMemsetAsync(nl, 0, 256 * sizeof(int), stream);
  nl_k<<<dim3(64), dim3(256), 0, stream>>>(gt, fov, nl);
  pass1_k<<<dim3(NB, 4, 2), dim3(256), 0, stream>>>(pred, predmv, gt, fov,
                                                    gpart, spart, qpart, NB, 512 / NB);
  const int tot = 2 * 36 * 256 + 2 * 4 * 32 * 256 + 2 * 4 * 64;
  reduce_k<<<dim3((tot + 255) / 256), dim3(256), 0, stream>>>(gpart, spart, qpart,
                                                              gred, sred, qred, NB);
  finalize_k<<<dim3(1), dim3(256), 0, stream>>>(gred, sred, qred, nl, out);
}